// Round 2
// baseline (321.576 us; speedup 1.0000x reference)
//
#include <hip/hip_runtime.h>
#include <math.h>

typedef float v2f __attribute__((ext_vector_type(2)));
typedef float v4f __attribute__((ext_vector_type(4)));

#define LT(i,j) ((i)*((i)+1)/2 + (j))

// reflect index into [0,512)
__device__ __forceinline__ int reflect512(int i) {
  int a = (i < 0) ? -i : i;
  int b = 1022 - a;
  return (a < b) ? a : b;
}

// ---- halo'd interleaved buffer: zb[b][520][520][12] f32, halo=4, reflected.
// pixel layout: [x0x1][x2x3][x4x5][y0y1][y2y3][y4y5] (3 x 16B)
constexpr int HB  = 520;          // 512 + 2*4 halo
constexpr int PS  = 12;           // words per pixel
constexpr int RS  = HB * PS;      // words per halo row (6240)

// 4 pixels per thread. Interior column-groups use dwordx4 loads from the
// planar inputs; only the edge groups take the reflect path.
__global__ __launch_bounds__(256)
void prep_interleave4(const float* __restrict__ xg, const float* __restrict__ yg,
                      float* __restrict__ zb) {
  constexpr int H = 512, W = 512, HW = H * W;
  constexpr int WQ = HB / 4;                  // 130 groups of 4 columns
  const int idx = blockIdx.x * 256 + threadIdx.x;
  if (idx >= 2 * HB * WQ) return;
  const int b  = idx / (HB * WQ);
  const int r2 = idx - b * (HB * WQ);
  const int hr = r2 / WQ;
  const int q  = r2 - hr * WQ;
  const int h  = reflect512(hr - 4);
  const int w0 = q * 4 - 4;                   // first source col (halo - 4)
  const size_t rowbase = (size_t)b * 6 * HW + (size_t)h * W;

  float xv[6][4], yv[6][4];
  if (w0 >= 0 && w0 + 3 < W) {
    #pragma unroll
    for (int c = 0; c < 6; ++c) {
      const v4f vx = *(const v4f*)(xg + rowbase + (size_t)c * HW + w0);
      const v4f vy = *(const v4f*)(yg + rowbase + (size_t)c * HW + w0);
      #pragma unroll
      for (int j = 0; j < 4; ++j) { xv[c][j] = vx[j]; yv[c][j] = vy[j]; }
    }
  } else {
    #pragma unroll
    for (int j = 0; j < 4; ++j) {
      const int w = reflect512(w0 + j);
      #pragma unroll
      for (int c = 0; c < 6; ++c) {
        xv[c][j] = xg[rowbase + (size_t)c * HW + w];
        yv[c][j] = yg[rowbase + (size_t)c * HW + w];
      }
    }
  }

  float* o = zb + ((size_t)(b * HB + hr) * HB + q * 4) * PS;
  #pragma unroll
  for (int j = 0; j < 4; ++j) {
    v4f p0 = {xv[0][j], xv[1][j], xv[2][j], xv[3][j]};
    v4f p1 = {xv[4][j], xv[5][j], yv[0][j], yv[1][j]};
    v4f p2 = {yv[2][j], yv[3][j], yv[4][j], yv[5][j]};
    *(v4f*)(o + j * PS + 0) = p0;
    *(v4f*)(o + j * PS + 4) = p1;
    *(v4f*)(o + j * PS + 8) = p2;
  }
}

// Gram entry g[a][b] (a>=b) from the 2x2-block pk accumulators.
__device__ __forceinline__ float gget(const v2f* accd, const v2f* accs,
                                      int a, int b) {
  const int t = LT(a >> 1, b >> 1);
  if (((a & 1) == 0) && ((b & 1) == 0)) return accd[t].x;
  if (((a & 1) == 1) && ((b & 1) == 1)) return accd[t].y;
  if ((a & 1) == 0) return accs[t].x;
  return accs[t].y;
}

// ---- DPP horizontal window reduction (within each 16-lane row).
// row_shr:N = 0x110 | N; bound_ctrl=true -> out-of-row reads 0.
template <int CTRL>
__device__ __forceinline__ float dppadd(float dsrc, float acc) {
  int d = __builtin_amdgcn_update_dpp(0, __float_as_int(dsrc), CTRL, 0xF, 0xF, true);
  return acc + __int_as_float(d);
}

// Left-aligned K-wide sum: lane t gets sum of lanes [t-K+1, t].
// MUST run with all lanes active (inactive DPP source lanes read as 0).
template <int K>
__device__ __forceinline__ float redK(float x) {
  if constexpr (K == 9) {
    float s = dppadd<0x111>(x, x);   // + shr1  -> lanes t-1..t
    s = dppadd<0x112>(s, s);         // + shr2  -> t-3..t
    s = dppadd<0x114>(s, s);         // + shr4  -> t-7..t
    s = dppadd<0x118>(x, s);         // + x[t-8] -> t-8..t (9 terms)
    return s;
  } else {                           // K == 5
    float s = dppadd<0x111>(x, x);   // t-1..t
    s = dppadd<0x112>(s, s);         // t-3..t
    s = dppadd<0x114>(x, s);         // + x[t-4] -> t-4..t (5 terms)
    return s;
  }
}

template <int K>
__device__ __forceinline__ float gget_r(const v2f* accd, const v2f* accs,
                                        int a, int b) {
  return redK<K>(gget(accd, accs, a, b));
}

// Packed-lower SPD 6x6 -> packed-lower L^{-1} in place. Divide/sqrt-free.
__device__ __forceinline__ void cholinv6(float* a) {
  #pragma unroll
  for (int j = 0; j < 6; ++j) {
    float d = a[LT(j,j)];
    #pragma unroll
    for (int p = 0; p < j; ++p) d -= a[LT(j,p)] * a[LT(j,p)];
    const float rd = __builtin_amdgcn_rsqf(d);
    a[LT(j,j)] = rd;
    #pragma unroll
    for (int i = j + 1; i < 6; ++i) {
      float s = a[LT(i,j)];
      #pragma unroll
      for (int p = 0; p < j; ++p) s -= a[LT(i,p)] * a[LT(j,p)];
      a[LT(i,j)] = s * rd;
    }
  }
  #pragma unroll
  for (int j = 0; j < 6; ++j) {
    #pragma unroll
    for (int i = j + 1; i < 6; ++i) {
      float s = 0.0f;
      #pragma unroll
      for (int p = j; p < i; ++p) s += a[LT(i,p)] * a[LT(p,j)];
      a[LT(i,j)] = -s * a[LT(i,i)];
    }
  }
}

// +/- one pixel's products into the per-lane COLUMN-state accumulators.
template <bool ADD>
__device__ __forceinline__ void px_acc(const float* __restrict__ p,
                                       v2f* zs, v2f* accd, v2f* accs) {
  const v4f l0 = *(const v4f*)(p + 0);
  const v4f l1 = *(const v4f*)(p + 4);
  const v4f l2 = *(const v4f*)(p + 8);
  v2f z[6];
  z[0] = l0.lo; z[1] = l0.hi;
  z[2] = l1.lo; z[3] = l1.hi;
  z[4] = l2.lo; z[5] = l2.hi;
  #pragma unroll
  for (int q = 0; q < 6; ++q) zs[q] = ADD ? (zs[q] + z[q]) : (zs[q] - z[q]);
  int t = 0;
  #pragma unroll
  for (int Kp = 0; Kp < 6; ++Kp) {
    #pragma unroll
    for (int Pp = 0; Pp <= Kp; ++Pp) {
      const v2f c  = z[Pp];
      const v2f cs = __builtin_shufflevector(c, c, 1, 0);
      const v2f a  = ADD ? z[Kp] : -z[Kp];
      accd[t] = __builtin_elementwise_fma(a, c,  accd[t]);
      accs[t] = __builtin_elementwise_fma(a, cs, accs[t]);
      ++t;
    }
  }
}

// emit from COLUMN states: horizontal window reduce (DPP) folded into the
// Gram fetches. Runs with all lanes active; only the caller's store is masked.
template <int K>
__device__ __forceinline__ float emit_sim_dpp(const v2f* zs, const v2f* accd,
                                              const v2f* accs) {
  constexpr float inv_n = 1.0f / (K * K);
  float mx[6], my[6];
  #pragma unroll
  for (int i = 0; i < 6; ++i) {
    mx[i] = redK<K>((i & 1) ? zs[i >> 1].y : zs[i >> 1].x) * inv_n;
    my[i] = redK<K>((i & 1) ? zs[3 + (i >> 1)].y : zs[3 + (i >> 1)].x) * inv_n;
  }
  float ax[21];
  {
    int t = 0;
    #pragma unroll
    for (int i = 0; i < 6; ++i)
      #pragma unroll
      for (int j = 0; j <= i; ++j) {
        const float e = (i == j) ? 1e-6f : 0.0f;
        ax[t] = gget_r<K>(accd, accs, i, j) * inv_n - mx[i] * mx[j] + e;
        ++t;
      }
  }
  cholinv6(ax);
  float ay[21];
  {
    int t = 0;
    #pragma unroll
    for (int i = 0; i < 6; ++i)
      #pragma unroll
      for (int j = 0; j <= i; ++j) {
        const float e = (i == j) ? 1e-6f : 0.0f;
        ay[t] = gget_r<K>(accd, accs, 6 + i, 6 + j) * inv_n - my[i] * my[j] + e;
        ++t;
      }
  }
  cholinv6(ay);
  float cxy[36];
  #pragma unroll
  for (int i = 0; i < 6; ++i)
    #pragma unroll
    for (int j = 0; j < 6; ++j)
      cxy[i * 6 + j] = fmaf(-mx[i], my[j], gget_r<K>(accd, accs, 6 + j, i) * inv_n);
  float sim = 0.0f;
  #pragma unroll
  for (int i = 0; i < 6; ++i) {
    float di = 0.0f;
    #pragma unroll
    for (int j = 0; j <= i; ++j) {
      float inner = 0.0f;
      #pragma unroll
      for (int k = i; k < 6; ++k) inner += cxy[j * 6 + k] * ay[LT(k, i)];
      di += ax[LT(i, j)] * inner;
    }
    sim += fabsf(di);
  }
  return sim * (1.0f / 6.0f);
}

// Column-state kernel: lane t of each 16-lane group owns halo column
// hc = gx0 + t + (4-R). Group produces (16-2R) output columns per y-step at
// lanes t >= 2R (output col c = gx0 + t - 2R). Vertical slide: +enter px,
// -leave px per step (2 pixel-product ops instead of 2K).
template <int R, int V>
__device__ __forceinline__ void run_dpp(const float* __restrict__ zb,
                                        float* __restrict__ out, int b, int ri) {
  constexpr int K = 2 * R + 1;
  constexpr int H = 512, W = 512;

  const int t  = threadIdx.x & 15;
  const int G  = threadIdx.x >> 4;                 // 16 groups per block
  const int gx0 = blockIdx.x * (16 - 2 * R);       // 8-wide (R4) / 12-wide (R2)
  const int hbase = ((int)blockIdx.y * 16 + G) * V;

  int hc = gx0 + t + (4 - R);
  if (hc > HB - 1) hc = HB - 1;   // R2 last tile only; contaminated lanes are masked
  const float* colbase = zb + (size_t)b * HB * RS + (size_t)hc * PS;

  v2f zs[6]    = {};
  v2f accd[21] = {};
  v2f accs[21] = {};

  // warm-up: build column state over the K window rows of output row hbase
  const float* pw = colbase + (size_t)(hbase + 4 - R) * RS;
  #pragma unroll 1
  for (int dy = 0; dy < K; ++dy) {
    px_acc<true>(pw, zs, accd, accs);
    pw += RS;
  }

  const int c0 = gx0 + t - 2 * R;
  const bool valid = (t >= 2 * R) && (c0 < W);

  {
    const float sim = emit_sim_dpp<K>(zs, accd, accs);
    if (valid)
      out[((size_t)((b * H + hbase) * W + c0)) * 2 + ri] = sim;
  }

  const float* pe = colbase + (size_t)(hbase + 5 + R) * RS;  // enter: row s+4+R
  const float* pl = colbase + (size_t)(hbase + 4 - R) * RS;  // leave: row s+3-R
  #pragma unroll 1
  for (int s = 1; s < V; ++s) {
    px_acc<true >(pe, zs, accd, accs); pe += RS;
    px_acc<false>(pl, zs, accd, accs); pl += RS;
    const float sim = emit_sim_dpp<K>(zs, accd, accs);
    if (valid)
      out[((size_t)((b * H + hbase + s) * W + c0)) * 2 + ri] = sim;
  }
}

// z 0,1: R=4 batch z (64 x-tiles of 8). z 2,3: R=2 batch z-2 (43 x-tiles of 12).
__global__ __launch_bounds__(256, 2)
void cca_dpp(const float* __restrict__ zb, float* __restrict__ out) {
  const int z = blockIdx.z;
  if (z < 2) {
    run_dpp<4, 8>(zb, out, z, 1);
  } else {
    if (blockIdx.x >= 43) return;   // 43*12 = 516 >= 512
    run_dpp<2, 8>(zb, out, z - 2, 0);
  }
}

extern "C" void kernel_launch(void* const* d_in, const int* in_sizes, int n_in,
                              void* d_out, int out_size, void* d_ws, size_t ws_size,
                              hipStream_t stream) {
  const float* x = (const float*)d_in[0];
  const float* y = (const float*)d_in[1];
  float* out = (float*)d_out;
  float* zb  = (float*)d_ws;   // needs 2*520*520*12*4 B = 25.96 MB

  {
    const int n = 2 * HB * (HB / 4);   // 4 px per thread
    prep_interleave4<<<dim3((n + 255) / 256), dim3(256), 0, stream>>>(x, y, zb);
  }
  dim3 grid(64, 4, 4);   // z<2: R4 (all 64 x-tiles); z>=2: R2 (43 used)
  cca_dpp<<<grid, dim3(256), 0, stream>>>(zb, out);
}

// Round 3
// 134.264 us; speedup vs baseline: 2.3951x; 2.3951x over previous
//
#include <hip/hip_runtime.h>
#include <math.h>

typedef float v2f __attribute__((ext_vector_type(2)));
typedef float v4f __attribute__((ext_vector_type(4)));

#define LT(i,j) ((i)*((i)+1)/2 + (j))

// reflect index into [0,512)
__device__ __forceinline__ int reflect512(int i) {
  int a = (i < 0) ? -i : i;
  int b = 1022 - a;
  return (a < b) ? a : b;
}

// ---- halo'd interleaved buffer: zb[b][520][520][12] f32, halo=4, reflected.
// pixel layout: [x0x1][x2x3][x4x5][y0y1][y2y3][y4y5] (3 x 16B)
constexpr int HB  = 520;          // 512 + 2*4 halo
constexpr int PS  = 12;           // words per pixel
constexpr int RS  = HB * PS;      // words per halo row (6240)

// 4 pixels per thread. Interior column-groups use dwordx4 loads from the
// planar inputs; only the edge groups take the reflect path.
__global__ __launch_bounds__(256)
void prep_interleave4(const float* __restrict__ xg, const float* __restrict__ yg,
                      float* __restrict__ zb) {
  constexpr int H = 512, W = 512, HW = H * W;
  constexpr int WQ = HB / 4;                  // 130 groups of 4 columns
  const int idx = blockIdx.x * 256 + threadIdx.x;
  if (idx >= 2 * HB * WQ) return;
  const int b  = idx / (HB * WQ);
  const int r2 = idx - b * (HB * WQ);
  const int hr = r2 / WQ;
  const int q  = r2 - hr * WQ;
  const int h  = reflect512(hr - 4);
  const int w0 = q * 4 - 4;                   // first source col (halo - 4)
  const size_t rowbase = (size_t)b * 6 * HW + (size_t)h * W;

  float xv[6][4], yv[6][4];
  if (w0 >= 0 && w0 + 3 < W) {
    #pragma unroll
    for (int c = 0; c < 6; ++c) {
      const v4f vx = *(const v4f*)(xg + rowbase + (size_t)c * HW + w0);
      const v4f vy = *(const v4f*)(yg + rowbase + (size_t)c * HW + w0);
      #pragma unroll
      for (int j = 0; j < 4; ++j) { xv[c][j] = vx[j]; yv[c][j] = vy[j]; }
    }
  } else {
    #pragma unroll
    for (int j = 0; j < 4; ++j) {
      const int w = reflect512(w0 + j);
      #pragma unroll
      for (int c = 0; c < 6; ++c) {
        xv[c][j] = xg[rowbase + (size_t)c * HW + w];
        yv[c][j] = yg[rowbase + (size_t)c * HW + w];
      }
    }
  }

  float* o = zb + ((size_t)(b * HB + hr) * HB + q * 4) * PS;
  #pragma unroll
  for (int j = 0; j < 4; ++j) {
    v4f p0 = {xv[0][j], xv[1][j], xv[2][j], xv[3][j]};
    v4f p1 = {xv[4][j], xv[5][j], yv[0][j], yv[1][j]};
    v4f p2 = {yv[2][j], yv[3][j], yv[4][j], yv[5][j]};
    *(v4f*)(o + j * PS + 0) = p0;
    *(v4f*)(o + j * PS + 4) = p1;
    *(v4f*)(o + j * PS + 8) = p2;
  }
}

// Gram entry g[a][b] (a>=b) from the 2x2-block pk accumulators.
__device__ __forceinline__ float gget(const v2f* accd, const v2f* accs,
                                      int a, int b) {
  const int t = LT(a >> 1, b >> 1);
  if (((a & 1) == 0) && ((b & 1) == 0)) return accd[t].x;
  if (((a & 1) == 1) && ((b & 1) == 1)) return accd[t].y;
  if ((a & 1) == 0) return accs[t].x;
  return accs[t].y;
}

// Packed-lower SPD 6x6 -> packed-lower L^{-1} in place. Divide/sqrt-free.
__device__ __forceinline__ void cholinv6(float* a) {
  #pragma unroll
  for (int j = 0; j < 6; ++j) {
    float d = a[LT(j,j)];
    #pragma unroll
    for (int p = 0; p < j; ++p) d -= a[LT(j,p)] * a[LT(j,p)];
    const float rd = __builtin_amdgcn_rsqf(d);
    a[LT(j,j)] = rd;
    #pragma unroll
    for (int i = j + 1; i < 6; ++i) {
      float s = a[LT(i,j)];
      #pragma unroll
      for (int p = 0; p < j; ++p) s -= a[LT(i,p)] * a[LT(j,p)];
      a[LT(i,j)] = s * rd;
    }
  }
  #pragma unroll
  for (int j = 0; j < 6; ++j) {
    #pragma unroll
    for (int i = j + 1; i < 6; ++i) {
      float s = 0.0f;
      #pragma unroll
      for (int p = j; p < i; ++p) s += a[LT(i,p)] * a[LT(p,j)];
      a[LT(i,j)] = -s * a[LT(i,i)];
    }
  }
}

// +/- one window row's K pixels into the pk Gram accumulators; p points at
// the row's first (leftmost) pixel. All loads are dwordx4 w/ imm offsets.
template <int K, bool ADD>
__device__ __forceinline__ void row_acc_g(const float* __restrict__ p,
                                          v2f* zs, v2f* accd, v2f* accs) {
  #pragma unroll
  for (int dx = 0; dx < K; ++dx) {
    const v4f l0 = *(const v4f*)(p + dx * PS + 0);
    const v4f l1 = *(const v4f*)(p + dx * PS + 4);
    const v4f l2 = *(const v4f*)(p + dx * PS + 8);
    v2f z[6];
    z[0] = l0.lo; z[1] = l0.hi;
    z[2] = l1.lo; z[3] = l1.hi;
    z[4] = l2.lo; z[5] = l2.hi;
    #pragma unroll
    for (int q = 0; q < 6; ++q) zs[q] = ADD ? (zs[q] + z[q]) : (zs[q] - z[q]);
    int t = 0;
    #pragma unroll
    for (int Kp = 0; Kp < 6; ++Kp) {
      #pragma unroll
      for (int Pp = 0; Pp <= Kp; ++Pp) {
        const v2f c  = z[Pp];
        const v2f cs = __builtin_shufflevector(c, c, 1, 0);
        const v2f a  = ADD ? z[Kp] : -z[Kp];
        accd[t] = __builtin_elementwise_fma(a, c,  accd[t]);
        accs[t] = __builtin_elementwise_fma(a, cs, accs[t]);
        ++t;
      }
    }
  }
}

// ---- emit, split in two for software pipelining ----
// extract: ALL reads of acc/zs happen here (cheap, load-free). After this the
// accumulators are dead to this output and may be updated for the next step.
template <int K>
__device__ __forceinline__ void extract_emit(const v2f* zs, const v2f* accd,
                                             const v2f* accs,
                                             float* ax, float* ay, float* cxy) {
  constexpr float inv_n = 1.0f / (K * K);
  float mx[6], my[6];
  #pragma unroll
  for (int i = 0; i < 6; ++i) {
    mx[i] = ((i & 1) ? zs[i >> 1].y : zs[i >> 1].x) * inv_n;
    my[i] = ((i & 1) ? zs[3 + (i >> 1)].y : zs[3 + (i >> 1)].x) * inv_n;
  }
  {
    int t = 0;
    #pragma unroll
    for (int i = 0; i < 6; ++i)
      #pragma unroll
      for (int j = 0; j <= i; ++j) {
        const float e = (i == j) ? 1e-6f : 0.0f;
        ax[t] = gget(accd, accs, i, j) * inv_n - mx[i] * mx[j] + e;
        ay[t] = gget(accd, accs, 6 + i, 6 + j) * inv_n - my[i] * my[j] + e;
        ++t;
      }
  }
  #pragma unroll
  for (int i = 0; i < 6; ++i)
    #pragma unroll
    for (int j = 0; j < 6; ++j)
      cxy[i * 6 + j] = fmaf(-mx[i], my[j], gget(accd, accs, 6 + j, i) * inv_n);
}

// finish: register-only serial math (2x cholinv + triangular solve + abs-sum).
__device__ __forceinline__ float finish_sim(float* ax, float* ay,
                                            const float* cxy) {
  cholinv6(ax);
  cholinv6(ay);
  float sim = 0.0f;
  #pragma unroll
  for (int i = 0; i < 6; ++i) {
    float di = 0.0f;
    #pragma unroll
    for (int j = 0; j <= i; ++j) {
      float inner = 0.0f;
      #pragma unroll
      for (int k = i; k < 6; ++k) inner += cxy[j * 6 + k] * ay[LT(k, i)];
      di += ax[LT(i, j)] * inner;
    }
    sim += fabsf(di);
  }
  return sim * (1.0f / 6.0f);
}

// One radius+batch per z. 16 tx x 16 strips, V=8 outputs per strip.
// Software-pipelined: iteration s issues step-s loads/FMAs BEFORE the serial
// cholesky of output s-1, so cache latency hides under the dependency chains.
template <int R, int V>
__device__ __forceinline__ void run(const float* __restrict__ zb,
                                    float* __restrict__ out, int b, int ri) {
  constexpr int K = 2 * R + 1;
  constexpr int H = 512, W = 512;

  const int h0 = blockIdx.y * (16 * V);
  const int w0 = blockIdx.x * 16;
  const int tx = threadIdx.x & 15;
  const int g  = threadIdx.x >> 4;
  const int hbase = h0 + g * V;
  const int wc = w0 + tx;

  // first pixel (leftmost col) of the top window row, in halo coords
  const float* base = zb + (size_t)b * HB * RS
                    + (size_t)(hbase + 4 - R) * RS + (size_t)(wc + 4 - R) * PS;

  v2f zs[6]    = {};
  v2f accd[21] = {};
  v2f accs[21] = {};

  #pragma unroll 1
  for (int dy = 0; dy < K; ++dy)
    row_acc_g<K, true>(base + dy * RS, zs, accd, accs);

  float ax[21], ay[21], cxy[36];
  extract_emit<K>(zs, accd, accs, ax, ay, cxy);   // output row hbase (s=0)

  #pragma unroll 1
  for (int s = 1; s < V; ++s) {
    // step-s window update: loads + FMAs issue first...
    row_acc_g<K, true >(base + (s + 2 * R) * RS, zs, accd, accs);  // entering
    row_acc_g<K, false>(base + (s - 1)     * RS, zs, accd, accs);  // leaving
    // ...then the serial math for output s-1 runs while loads are in flight.
    out[((size_t)((b * H + hbase + s - 1) * W + wc)) * 2 + ri] =
        finish_sim(ax, ay, cxy);
    extract_emit<K>(zs, accd, accs, ax, ay, cxy);  // output row hbase+s
  }
  out[((size_t)((b * H + hbase + V - 1) * W + wc)) * 2 + ri] =
      finish_sim(ax, ay, cxy);
}

// z in {0,1}: r=2 batch z; z in {2,3}: r=4 batch z-2. No LDS, no barriers.
__global__ __launch_bounds__(256, 2)
void cca_pipe(const float* __restrict__ zb, float* __restrict__ out) {
  const int z = blockIdx.z;
  if (z < 2) run<2, 8>(zb, out, z, 0);
  else       run<4, 8>(zb, out, z - 2, 1);
}

extern "C" void kernel_launch(void* const* d_in, const int* in_sizes, int n_in,
                              void* d_out, int out_size, void* d_ws, size_t ws_size,
                              hipStream_t stream) {
  const float* x = (const float*)d_in[0];
  const float* y = (const float*)d_in[1];
  float* out = (float*)d_out;
  float* zb  = (float*)d_ws;   // needs 2*520*520*12*4 B = 25.96 MB

  {
    const int n = 2 * HB * (HB / 4);   // 4 px per thread
    prep_interleave4<<<dim3((n + 255) / 256), dim3(256), 0, stream>>>(x, y, zb);
  }
  dim3 grid(512 / 16, 512 / (16 * 8), 4);   // 32 x 4 x 4 = 512 blocks
  cca_pipe<<<grid, dim3(256), 0, stream>>>(zb, out);
}